// Round 1
// baseline (16187.819 us; speedup 1.0000x reference)
//
#include <hip/hip_runtime.h>
#include <cmath>

#define HH 48
#define WW 48
#define HWSZ 2304
#define BB 8
#define TT 32

// Fused ConvLSTM step: gates = conv3x3(concat(x, h_prev), w) + bias, then
// LSTM pointwise update. One block = (16-row tile) x (one out channel) x (one batch).
// 192 threads = 48 cols x 4; each thread computes 4 consecutive output rows,
// all 4 gates.
template<int CIN, int CHID>
__global__ __launch_bounds__(192) void convlstm_step(
    const float* __restrict__ xin, long xbstride,   // x-part, per-batch stride
    const float* __restrict__ hin,                  // [B][CHID][HW] h_prev
    const float* __restrict__ w,                    // [4*CHID][CIN+CHID][3][3]
    const float* __restrict__ bias,                 // [4*CHID]
    float* __restrict__ cstate,                     // [B][CHID][HW], in-place
    float* __restrict__ hout,                       // [B][CHID][HW]
    float* __restrict__ seq_t)                      // if !=null and b==0: [CHID][HW]
{
    constexpr int CTOT  = CIN + CHID;
    constexpr int CHUNK = 4;
    constexpr int CTOTR = ((CTOT + CHUNK - 1) / CHUNK) * CHUNK;

    __shared__ float wlds[CTOTR * 36];          // [ic][gate*9 + k]
    __shared__ float tile[CHUNK][18][50];       // rows ty0-1..ty0+16, cols -1..48

    const int tx  = threadIdx.x;       // 0..47
    const int ty  = threadIdx.y;       // 0..3
    const int tid = ty * 48 + tx;      // 0..191
    const int ty0 = blockIdx.x * 16;   // tile row base
    const int c   = blockIdx.y;        // out channel
    const int b   = blockIdx.z;        // batch

    // Stage all weights for this out-channel (4 gates), zero-pad ic >= CTOT.
    for (int idx = tid; idx < CTOTR * 36; idx += 192) {
        int ic = idx / 36, r = idx - ic * 36;
        int g = r / 9, k = r - g * 9;
        float v = 0.f;
        if (ic < CTOT)
            v = w[(((long)(g * CHID + c)) * CTOT + ic) * 9 + k];
        wlds[idx] = v;
    }

    float acc[4][4];   // [pixel-row][gate]
    #pragma unroll
    for (int i = 0; i < 4; ++i)
        #pragma unroll
        for (int j = 0; j < 4; ++j) acc[i][j] = 0.f;

    const float* xb = xin + (long)b * xbstride;
    const float* hb = hin + (long)b * CHID * HWSZ;

    for (int ic0 = 0; ic0 < CTOT; ic0 += CHUNK) {
        __syncthreads();
        // Stage CHUNK input channels with halo (zero padding outside image).
        for (int idx = tid; idx < CHUNK * 18 * 50; idx += 192) {
            int chi = idx / 900;
            int rem = idx - chi * 900;
            int row = rem / 50;
            int col = rem - row * 50;
            int gy = ty0 - 1 + row;
            int gx = col - 1;
            int ic = ic0 + chi;
            float v = 0.f;
            if (ic < CTOT && gy >= 0 && gy < HH && gx >= 0 && gx < WW) {
                v = (ic < CIN) ? xb[ic * HWSZ + gy * WW + gx]
                               : hb[(ic - CIN) * HWSZ + gy * WW + gx];
            }
            tile[chi][row][col] = v;
        }
        __syncthreads();

        #pragma unroll
        for (int chi = 0; chi < CHUNK; ++chi) {
            const int ic = ic0 + chi;
            // 6 input rows x 3 cols cover this thread's 4 output rows.
            float vin[6][3];
            #pragma unroll
            for (int rr = 0; rr < 6; ++rr)
                #pragma unroll
                for (int cc = 0; cc < 3; ++cc)
                    vin[rr][cc] = tile[chi][ty * 4 + rr][tx + cc];
            // 36 weights (4 gates x 9 taps) via vectorized broadcast reads.
            const float4* wp = (const float4*)&wlds[ic * 36];
            float wv[36];
            #pragma unroll
            for (int q = 0; q < 9; ++q) {
                float4 f = wp[q];
                wv[q * 4 + 0] = f.x; wv[q * 4 + 1] = f.y;
                wv[q * 4 + 2] = f.z; wv[q * 4 + 3] = f.w;
            }
            #pragma unroll
            for (int g = 0; g < 4; ++g)
                #pragma unroll
                for (int rr = 0; rr < 4; ++rr)
                    #pragma unroll
                    for (int k = 0; k < 9; ++k)
                        acc[rr][g] += vin[rr + k / 3][k % 3] * wv[g * 9 + k];
        }
    }

    // LSTM pointwise update (gate order: i, f, o, g).
    const float bi = bias[c];
    const float bf = bias[CHID + c];
    const float bo = bias[2 * CHID + c];
    const float bg = bias[3 * CHID + c];
    #pragma unroll
    for (int rr = 0; rr < 4; ++rr) {
        int y = ty0 + ty * 4 + rr;
        long off = ((long)(b * CHID + c)) * HWSZ + y * WW + tx;
        float i_ = 1.f / (1.f + __expf(-(acc[rr][0] + bi)));
        float f_ = 1.f / (1.f + __expf(-(acc[rr][1] + bf)));
        float o_ = 1.f / (1.f + __expf(-(acc[rr][2] + bo)));
        float g_ = tanhf(acc[rr][3] + bg);
        float cp = cstate[off];
        float cn = f_ * cp + i_ * g_;
        float hn = o_ * tanhf(cn);
        cstate[off] = cn;
        hout[off] = hn;
        if (seq_t != nullptr && b == 0)
            seq_t[c * HWSZ + y * WW + tx] = hn;
    }
}

// out[k] = bl + sum_j wl[j] * seq_flat[32k + j]
__global__ void head_kernel(const float* __restrict__ seq,
                            const float* __restrict__ wl,
                            const float* __restrict__ bl,
                            float* __restrict__ out, int n)
{
    __shared__ float wls[32];
    if (threadIdx.x < 32) wls[threadIdx.x] = wl[threadIdx.x];
    __syncthreads();
    int k = blockIdx.x * 256 + threadIdx.x;
    if (k >= n) return;
    const float4* p = (const float4*)(seq + (long)k * 32);
    float s = bl[0];
    #pragma unroll
    for (int q = 0; q < 8; ++q) {
        float4 f = p[q];
        s += f.x * wls[q * 4 + 0] + f.y * wls[q * 4 + 1]
           + f.z * wls[q * 4 + 2] + f.w * wls[q * 4 + 3];
    }
    out[k] = s;
}

extern "C" void kernel_launch(void* const* d_in, const int* in_sizes, int n_in,
                              void* d_out, int out_size, void* d_ws, size_t ws_size,
                              hipStream_t stream)
{
    const float* x  = (const float*)d_in[0];   // [8,32,1,48,48]
    const float* w0 = (const float*)d_in[1];   // [256,65,3,3]
    const float* b0 = (const float*)d_in[2];   // [256]
    const float* w1 = (const float*)d_in[3];   // [128,96,3,3]
    const float* b1 = (const float*)d_in[4];   // [128]
    const float* wl = (const float*)d_in[5];   // [1,32]
    const float* bl = (const float*)d_in[6];   // [1]
    float* out = (float*)d_out;                // [73728]

    float* ws = (float*)d_ws;
    const long n0 = 8L * 64 * HWSZ;   // 1179648
    const long n1 = 8L * 32 * HWSZ;   // 589824
    float* h0a = ws; ws += n0;
    float* h0b = ws; ws += n0;
    float* c0  = ws; ws += n0;
    float* h1a = ws; ws += n1;
    float* h1b = ws; ws += n1;
    float* c1  = ws; ws += n1;
    float* seq = ws; ws += 32L * 32 * HWSZ;    // [T][32][2304] for batch 0

    // Zero initial states every call (deterministic; ws is not re-poisoned).
    hipMemsetAsync(h0a, 0, n0 * 4, stream);
    hipMemsetAsync(c0,  0, n0 * 4, stream);
    hipMemsetAsync(h1a, 0, n1 * 4, stream);
    hipMemsetAsync(c1,  0, n1 * 4, stream);

    float* h0c = h0a; float* h0n = h0b;
    float* h1c = h1a; float* h1n = h1b;
    for (int t = 0; t < TT; ++t) {
        convlstm_step<1, 64><<<dim3(3, 64, BB), dim3(48, 4), 0, stream>>>(
            x + (long)t * HWSZ, (long)TT * HWSZ, h0c, w0, b0, c0, h0n, nullptr);
        convlstm_step<64, 32><<<dim3(3, 32, BB), dim3(48, 4), 0, stream>>>(
            h0n, (long)64 * HWSZ, h1c, w1, b1, c1, h1n,
            seq + (long)t * 32 * HWSZ);
        float* tmp;
        tmp = h0c; h0c = h0n; h0n = tmp;
        tmp = h1c; h1c = h1n; h1n = tmp;
    }
    head_kernel<<<(73728 + 255) / 256, 256, 0, stream>>>(seq, wl, bl, out, 73728);
}